// Round 6
// baseline (286.287 us; speedup 1.0000x reference)
//
#include <hip/hip_runtime.h>

#define DIM   64
#define KCB   1024
#define RPB   128          // rows per block

// ws layout (floats): ws[0] = loss accumulator; ws[256..1279] = csq[k]

__global__ void vq_prep(const float* __restrict__ cb, float* __restrict__ ws) {
    int k = blockIdx.x * blockDim.x + threadIdx.x;
    if (k < KCB) {
        const float* e = cb + (k << 6);
        {
            #pragma clang fp contract(off)
            float racc[8];
            #pragma unroll
            for (int j = 0; j < 8; ++j) racc[j] = e[j] * e[j];
            #pragma unroll
            for (int t = 1; t < 8; ++t) {
                #pragma unroll
                for (int j = 0; j < 8; ++j) racc[j] += e[8 * t + j] * e[8 * t + j];
            }
            ws[256 + k] = ((racc[0] + racc[1]) + (racc[2] + racc[3]))
                        + ((racc[4] + racc[5]) + (racc[6] + racc[7]));
        }
    }
    if (k == 0) ws[0] = 0.0f;
}

// 2D register-tiled VQ kernel, occupancy-tuned vs R5:
//  - 128 rows/block, static 36.5 KB LDS -> 4 blocks/CU = 16 waves/CU
//    (R5: 73 KB -> 2 blocks/CU, VALUBusy 66% from uncovered lgkm waits).
//  - wave q scans entry quarter [q*256, q*256+256); e loads are wave-uniform
//    (readfirstlane) -> s_load_dwordx4 broadcast on the scalar pipe.
//  - lane tile: 2 rows x 32 entries (64 acc). Per jb step: 2 ds_read_b128 +
//    32 uniform float4 e-loads + 256 fmas -> same fma density as R5 with
//    4x less x-LDS traffic per entry.
//  - numerics: per-dot j-chain strictly sequential, d=(A-2m)+cs, argmin
//    ascending strict-<, quarters combined ascending (bit-identical to R5).
__global__ __launch_bounds__(256, 4) void vq_main(
        const float* __restrict__ in,
        const float* __restrict__ cb,
        const float* __restrict__ csq,      // = ws + 256
        float* __restrict__ codes_f,
        float* __restrict__ out,
        float* __restrict__ loss_acc)       // = ws + 0
{
    __shared__ float xs[RPB * DIM];         // 8192 words, swizzled x (32 KB)
    __shared__ float dtab[RPB * 4];         // per-row per-quarter best d (2 KB)
    __shared__ int   ktab[RPB * 4];         // per-row per-quarter best k (2 KB)
    __shared__ int   codes[RPB];            // 0.5 KB

    const int tid  = threadIdx.x;
    const int lane = tid & 63;
    const int q    = __builtin_amdgcn_readfirstlane(tid >> 6);   // entry quarter
    const size_t rowBase = (size_t)blockIdx.x * RPB;

    // ---- stage x, swizzled: word = row*64 + ((cj ^ (row&15))<<2) ----
    {
        const float4* gx = (const float4*)(in + rowBase * DIM);
        #pragma unroll
        for (int i = 0; i < 8; ++i) {
            int idx = i * 256 + tid;
            int row = idx >> 4, cj = idx & 15;
            float4 v = gx[idx];
            *(float4*)(xs + row * 64 + ((cj ^ (row & 15)) << 2)) = v;
        }
    }
    __syncthreads();

    // ---- A = ||x||^2 for my 2 rows (exact numpy pairwise-8 order) ----
    float A[2];
    #pragma unroll
    for (int ri = 0; ri < 2; ++ri) {
        const int row = lane + (ri << 6);       // (row&15) == (lane&15)
        float xv[64];
        #pragma unroll
        for (int cj = 0; cj < 16; ++cj) {
            float4 v = *(const float4*)(xs + row * 64 + ((cj ^ (lane & 15)) << 2));
            xv[cj*4+0]=v.x; xv[cj*4+1]=v.y; xv[cj*4+2]=v.z; xv[cj*4+3]=v.w;
        }
        {
            #pragma clang fp contract(off)
            float racc[8];
            #pragma unroll
            for (int j = 0; j < 8; ++j) racc[j] = xv[j] * xv[j];
            #pragma unroll
            for (int t = 1; t < 8; ++t) {
                #pragma unroll
                for (int j = 0; j < 8; ++j) racc[j] += xv[8*t+j] * xv[8*t+j];
            }
            A[ri] = ((racc[0] + racc[1]) + (racc[2] + racc[3]))
                  + ((racc[4] + racc[5]) + (racc[6] + racc[7]));
        }
    }

    // ---- main scan: my quarter's 256 entries, 32 at a time ----
    const float* cbq   = cb  + ((size_t)q << 14);   // q*256 entries * 64
    const float* csq_q = csq + (q << 8);
    float dmin[2] = {3.402823466e38f, 3.402823466e38f};
    int   kmin[2] = {0, 0};
    const int xb = lane * 64;

    #pragma unroll 1
    for (int ke = 0; ke < 256; ke += 32) {
        float m[2][32];
        #pragma unroll
        for (int ri = 0; ri < 2; ++ri)
            #pragma unroll
            for (int e = 0; e < 32; ++e) m[ri][e] = 0.0f;

        #pragma unroll 1
        for (int jb = 0; jb < 64; jb += 4) {
            const int slot4 = ((jb >> 2) ^ (lane & 15)) << 2;
            float4 a0 = *(const float4*)(xs + xb +        slot4);
            float4 a1 = *(const float4*)(xs + xb + 4096 + slot4);   // row lane+64
            #pragma unroll
            for (int e = 0; e < 32; ++e) {
                float4 ev = *(const float4*)(cbq + ((ke + e) << 6) + jb); // uniform
                m[0][e] = __builtin_fmaf(a0.x, ev.x, m[0][e]);
                m[0][e] = __builtin_fmaf(a0.y, ev.y, m[0][e]);
                m[0][e] = __builtin_fmaf(a0.z, ev.z, m[0][e]);
                m[0][e] = __builtin_fmaf(a0.w, ev.w, m[0][e]);
                m[1][e] = __builtin_fmaf(a1.x, ev.x, m[1][e]);
                m[1][e] = __builtin_fmaf(a1.y, ev.y, m[1][e]);
                m[1][e] = __builtin_fmaf(a1.z, ev.z, m[1][e]);
                m[1][e] = __builtin_fmaf(a1.w, ev.w, m[1][e]);
            }
        }

        #pragma unroll
        for (int e = 0; e < 32; ++e) {
            float cse = csq_q[ke + e];              // uniform
            int gk = (q << 8) + ke + e;
            #pragma unroll
            for (int ri = 0; ri < 2; ++ri) {
                float d;
                {
                    #pragma clang fp contract(off)
                    d = (A[ri] - 2.0f * m[ri][e]) + cse;
                }
                if (d < dmin[ri]) { dmin[ri] = d; kmin[ri] = gk; }  // ascending, strict <
            }
        }
    }

    // ---- cross-quarter lex-min combine ----
    #pragma unroll
    for (int ri = 0; ri < 2; ++ri) {
        int row = lane + (ri << 6);
        dtab[row * 4 + q] = dmin[ri];
        ktab[row * 4 + q] = kmin[ri];
    }
    __syncthreads();

    float db = 0.0f;
    if (tid < RPB) {
        float dbest = dtab[tid * 4];
        int   kbest = ktab[tid * 4];
        #pragma unroll
        for (int qq = 1; qq < 4; ++qq) {    // ascending quarters, strict <
            float dq = dtab[tid * 4 + qq];
            int   kq = ktab[tid * 4 + qq];
            if (dq < dbest) { dbest = dq; kbest = kq; }
        }
        codes[tid] = kbest;
        codes_f[rowBase + tid] = (float)kbest;
        db = dbest;
    }
    __syncthreads();

    // ---- fused straight-through write: st = x + (q - x) ----
    {
        float4* gout = (float4*)(out + rowBase * DIM);
        #pragma unroll
        for (int i = 0; i < 8; ++i) {
            int idx = i * 256 + tid;
            int row = idx >> 4, cj = idx & 15;
            int code = codes[row];
            float4 qv = *(const float4*)(cb + ((size_t)code << 6) + (cj << 2));
            float4 xv = *(const float4*)(xs + row * 64 + ((cj ^ (row & 15)) << 2));
            float4 st;
            {
                #pragma clang fp contract(off)
                st.x = xv.x + (qv.x - xv.x);
                st.y = xv.y + (qv.y - xv.y);
                st.z = xv.z + (qv.z - xv.z);
                st.w = xv.w + (qv.w - xv.w);
            }
            gout[idx] = st;
        }
    }

    // ---- loss partial (dtab reused as reduction tree; tid>=128 contribute 0) ----
    __syncthreads();
    dtab[tid] = db;
    __syncthreads();
    #pragma unroll
    for (int s = 128; s > 0; s >>= 1) {
        if (tid < s) dtab[tid] += dtab[tid + s];
        __syncthreads();
    }
    if (tid == 0) atomicAdd(loss_acc, dtab[0]);
}

__global__ void vq_final(const float* __restrict__ ws, float* __restrict__ loss_out) {
    // loss = codebook_loss + BETA*commitment = 1.25 * mean((x-q)^2)
    loss_out[0] = 1.25f * ws[0] / 8388608.0f;
}

extern "C" void kernel_launch(void* const* d_in, const int* in_sizes, int n_in,
                              void* d_out, int out_size, void* d_ws, size_t ws_size,
                              hipStream_t stream) {
    const float* in = (const float*)d_in[0];   // (32,4096,64) fp32
    const float* cb = (const float*)d_in[1];   // (1024,64)    fp32
    float* out     = (float*)d_out;
    float* codes_f = out + 8388608;
    float* loss_p  = out + 8519680;
    float* ws      = (float*)d_ws;

    vq_prep <<<4,    256, 0, stream>>>(cb, ws);
    vq_main <<<1024, 256, 0, stream>>>(in, cb, ws + 256, codes_f, out, ws);
    vq_final<<<1,    1,   0, stream>>>(ws, loss_p);
}